// Round 12
// baseline (245.095 us; speedup 1.0000x reference)
//
#include <hip/hip_runtime.h>
#include <math.h>

// EdgeGAT: B=8, OP=400, MA=200, F=64. f32 in/out, adj int32.
// v5 (5th submit — infra failures, never measured): FULL single-kernel fusion.
//  - per-block W@a (192 threads x 64 FMA, W L2-resident)
//  - e_ma: one 64-dot of y[bm] per wave (6 shuffles)
//  - e_op folded into the stream dot: s = z4.we_q + x4.wop_q reduced by the
//    SAME 4 intra-16 shuffles (x row already loaded for u) -> no ws_eop,
//    no per-entry e in LDS (pad test is idx<cnt), no workspace at all.
// Keeps v4's levers: depth-1 register prefetch, dual softmax states,
// single-exp update. Block=(b,m), 4 waves x 100 rows, quad-of-16 layout.
#define B_   8
#define OP_  400
#define MA_  200
#define ZROW (MA_ * 64)
#define NEGM -1.0e30f

typedef float v4f __attribute__((ext_vector_type(4)));

__global__ __launch_bounds__(256) void gat_one(
    const float* __restrict__ x, const float* __restrict__ y,
    const float* __restrict__ z, const int* __restrict__ adj,
    const float* __restrict__ Wop, const float* __restrict__ Wma,
    const float* __restrict__ Wedge, const float* __restrict__ att,
    float* __restrict__ out)
{
    __shared__ float w_s[192];         // [0:64)=w_op, [64:128)=w_ma, [128:192)=w_e
    __shared__ int   nls[4][112];      // compacted active n per wave (+ sentinels)
    __shared__ float mred[4], lred[4];
    __shared__ float vws[4][64], uws[4][64];
    __shared__ float vs_s[64], us_s[64], ys_s[64];
    __shared__ float pvt[4][64];

    const int tid = threadIdx.x, wv = tid >> 6, ln = tid & 63;
    const int g = ln >> 4, q = ln & 15;            // group / feature-quad
    const int bm = blockIdx.x;
    const int b = bm / MA_, m = bm % MA_;

    // ---- per-block W@a: w_s[which*64+i] = dot(W[which][i,:], a[which]) ----
    if (tid < 192) {
        const int which = tid >> 6, i = tid & 63;
        const float* W = (which == 0) ? Wop : ((which == 1) ? Wma : Wedge);
        const float* a = att + which * 64;
        float acc = 0.f;
        #pragma unroll 8
        for (int f = 0; f < 64; ++f) acc = fmaf(W[i * 64 + f], a[f], acc);
        w_s[tid] = acc;
    }

    // ---- per-wave active-row compaction (rows rbase..rbase+99) ----
    const int rbase = wv * 100;
    int cnt = 0;
    #pragma unroll
    for (int round = 0; round < 2; ++round) {
        const int lr = round * 64 + ln;            // 0..127
        const int n  = rbase + lr;
        bool a = false;
        if (lr < 100) a = (adj[((size_t)(b * OP_ + n)) * MA_ + m] != 0);
        const unsigned long long mask = __ballot(a);
        if (a) {
            const int pos = cnt + __popcll(mask & ((1ull << ln) - 1ull));
            nls[wv][pos] = n;
        }
        cnt += __popcll(mask);
    }
    // pad through cnt_p+8 with valid-address sentinels (depth-1 prefetch safe)
    const int cnt_p = (cnt + 7) & ~7;              // <= 104
    if (ln < cnt_p + 8 - cnt) nls[wv][cnt + ln] = rbase;

    __syncthreads();                               // w_s ready

    const v4f wqe = ((const v4f*)(w_s + 128))[q];  // w_e quad
    const v4f wqo = ((const v4f*)(w_s      ))[q];  // w_op quad

    // e_ma: redundant per wave; xor folds leave the sum in all lanes
    float ema = y[(size_t)bm * 64 + ln] * w_s[64 + ln];
    #pragma unroll
    for (int o = 32; o > 0; o >>= 1) ema += __shfl_xor(ema, o, 64);

    const float* zP = z + ((size_t)b * OP_ * MA_ + m) * 64;
    const float* xP = x + (size_t)b * OP_ * 64;

    // dual independent states (a-rows / b-rows) per group
    v4f v0 = {0.f,0.f,0.f,0.f}, u0 = {0.f,0.f,0.f,0.f};
    v4f v1 = {0.f,0.f,0.f,0.f}, u1 = {0.f,0.f,0.f,0.f};
    float M0 = NEGM, L0 = 0.f, M1 = NEGM, L1 = 0.f;

    // single-exp online-softmax update; 4 intra-16 shuffles shared by quad.
    // s = z.we + x.wop accumulated per-lane BEFORE the reduction.
    auto upd = [&wqe, &wqo](float& M, float& L, v4f& v, v4f& u,
                            const v4f z4, const v4f x4, const float eo) {
        float s_ = fmaf(z4.x, wqe.x, fmaf(z4.y, wqe.y,
                   fmaf(z4.z, wqe.z, z4.w * wqe.w)));
        s_ = fmaf(x4.x, wqo.x, fmaf(x4.y, wqo.y,
             fmaf(x4.z, wqo.z, fmaf(x4.w, wqo.w, s_))));
        s_ += __shfl_xor(s_, 1, 64); s_ += __shfl_xor(s_, 2, 64);
        s_ += __shfl_xor(s_, 4, 64); s_ += __shfl_xor(s_, 8, 64);
        float e_ = s_ + eo;                        // eo = ema (real) | NEGM (pad)
        e_ = (e_ >= 0.f) ? e_ : 0.01f * e_;        // leaky_relu
        const float m2_ = fmaxf(M, e_);
        const float w_  = __expf(fminf(M, e_) - m2_);   // one exp
        const bool  nm  = (e_ > M);
        const float c_  = nm ? w_ : 1.f;
        const float p_  = nm ? 1.f : w_;
        L = fmaf(L, c_, p_);
        v = v * c_ + z4 * p_;
        u = u * c_ + x4 * p_;
        M = m2_;
    };

    // ---- streaming pass: 8 rows/iter, depth-1 prefetch ----
    int pa = nls[wv][g];
    int pb = nls[wv][4 + g];
    v4f za = __builtin_nontemporal_load((const v4f*)(zP + (size_t)pa * ZROW) + q);
    v4f zb = __builtin_nontemporal_load((const v4f*)(zP + (size_t)pb * ZROW) + q);
    v4f xa = *((const v4f*)(xP + ((size_t)pa << 6)) + q);
    v4f xb = *((const v4f*)(xP + ((size_t)pb << 6)) + q);

    for (int i = 0; i < cnt_p; i += 8) {
        const int qa = nls[wv][i + 8 + g];         // prefetch next (sentinel-safe)
        const int qb = nls[wv][i + 12 + g];
        const v4f nza = __builtin_nontemporal_load((const v4f*)(zP + (size_t)qa * ZROW) + q);
        const v4f nzb = __builtin_nontemporal_load((const v4f*)(zP + (size_t)qb * ZROW) + q);
        const v4f nxa = *((const v4f*)(xP + ((size_t)qa << 6)) + q);
        const v4f nxb = *((const v4f*)(xP + ((size_t)qb << 6)) + q);
        const float ea = (i + g     < cnt) ? ema : NEGM;
        const float eb = (i + 4 + g < cnt) ? ema : NEGM;
        upd(M0, L0, v0, u0, za, xa, ea);
        upd(M1, L1, v1, u1, zb, xb, eb);
        pa = qa; pb = qb; za = nza; zb = nzb; xa = nxa; xb = nxb;
    }

    // ---- merge dual states ----
    const float Mp = fmaxf(M0, M1);
    const float ca = __expf(M0 - Mp), cb = __expf(M1 - Mp);
    float L = L0 * ca + L1 * cb;
    v4f  v = v0 * ca + v1 * cb;
    v4f  u = u0 * ca + u1 * cb;
    float M = Mp;

    // ---- merge the 4 groups within the wave (xor folds over 16/32) ----
    float Mw = M;
    Mw = fmaxf(Mw, __shfl_xor(Mw, 16, 64));
    Mw = fmaxf(Mw, __shfl_xor(Mw, 32, 64));
    const float cg = __expf(M - Mw);               // per-group rescale
    float Lw = L * cg;
    Lw += __shfl_xor(Lw, 16, 64);
    Lw += __shfl_xor(Lw, 32, 64);
    v *= cg;
    u *= cg;
    v.x += __shfl_xor(v.x, 16, 64); v.y += __shfl_xor(v.y, 16, 64);
    v.z += __shfl_xor(v.z, 16, 64); v.w += __shfl_xor(v.w, 16, 64);
    v.x += __shfl_xor(v.x, 32, 64); v.y += __shfl_xor(v.y, 32, 64);
    v.z += __shfl_xor(v.z, 32, 64); v.w += __shfl_xor(v.w, 32, 64);
    u.x += __shfl_xor(u.x, 16, 64); u.y += __shfl_xor(u.y, 16, 64);
    u.z += __shfl_xor(u.z, 16, 64); u.w += __shfl_xor(u.w, 16, 64);
    u.x += __shfl_xor(u.x, 32, 64); u.y += __shfl_xor(u.y, 32, 64);
    u.z += __shfl_xor(u.z, 32, 64); u.w += __shfl_xor(u.w, 32, 64);

    if (ln < 16) {
        ((v4f*)vws[wv])[q] = v;
        ((v4f*)uws[wv])[q] = u;
    }
    if (ln == 0) { mred[wv] = Mw; lred[wv] = Lw; }
    __syncthreads();

    // ---- cross-wave online-softmax merge ----
    if (tid < 64) {
        const float Mg = fmaxf(fmaxf(mred[0], mred[1]), fmaxf(mred[2], mred[3]));
        const float c0 = __expf(mred[0] - Mg);
        const float c1 = __expf(mred[1] - Mg);
        const float c2 = __expf(mred[2] - Mg);
        const float c3 = __expf(mred[3] - Mg);
        const float Lg = c0 * lred[0] + c1 * lred[1] + c2 * lred[2] + c3 * lred[3];
        const float inv = (Lg > 0.f) ? (1.f / Lg) : 0.f;   // row_empty -> 0
        vs_s[tid] = (c0 * vws[0][tid] + c1 * vws[1][tid] +
                     c2 * vws[2][tid] + c3 * vws[3][tid]) * inv;
        us_s[tid] = (c0 * uws[0][tid] + c1 * uws[1][tid] +
                     c2 * uws[2][tid] + c3 * uws[3][tid]) * inv;
        ys_s[tid] = y[(size_t)bm * 64 + tid];
    }
    __syncthreads();

    // ---- fused epilogue: h = v@We + u@Wop + y@Wma ; waves split i ----
    {
        float acc = 0.f;
        const int i0 = wv * 16;
        #pragma unroll
        for (int k = 0; k < 16; ++k) {
            const int i = i0 + k;
            acc += vs_s[i] * Wedge[i * 64 + ln]
                 + us_s[i] * Wop[i * 64 + ln]
                 + ys_s[i] * Wma[i * 64 + ln];
        }
        pvt[wv][ln] = acc;
    }
    __syncthreads();
    if (tid < 64) {
        const float h = pvt[0][tid] + pvt[1][tid] + pvt[2][tid] + pvt[3][tid];
        out[(size_t)bm * 64 + tid] = (h > 0.f) ? h : (__expf(h) - 1.f);
    }
}

extern "C" void kernel_launch(void* const* d_in, const int* in_sizes, int n_in,
                              void* d_out, int out_size, void* d_ws, size_t ws_size,
                              hipStream_t stream) {
    const float* x     = (const float*)d_in[0];
    const float* y     = (const float*)d_in[1];
    const float* z     = (const float*)d_in[2];
    const int*   adj   = (const int*)d_in[3];
    const float* Wop   = (const float*)d_in[4];
    const float* Wma   = (const float*)d_in[5];
    const float* Wedge = (const float*)d_in[6];
    const float* att   = (const float*)d_in[7];
    (void)d_ws; (void)ws_size;

    gat_one<<<B_ * MA_, 256, 0, stream>>>(
        x, y, z, adj, Wop, Wma, Wedge, att, (float*)d_out);
}

// Round 13
// 239.097 us; speedup vs baseline: 1.0251x; 1.0251x over previous
//
#include <hip/hip_runtime.h>
#include <math.h>

// EdgeGAT: B=8, OP=400, MA=200, F=64. f32 in/out, adj int32.
// v6 = REVERT to v4 (best measured: 235.0 µs). v5's single-kernel fusion
// REGRESSED to 245.1: the fused per-block W@a prologue serialized 1600
// redundant 64-deep FMA chains + barrier ahead of the z-stream, costing more
// than the launch it saved. Keeping the 2-kernel structure:
//  precompute_k: w_e/w_op/w_ma@a + e_op/e_ma (1200 trivial parallel blocks)
//  gat_fused:    per-wave compaction -> quad-of-16 stream over z with
//                depth-1 register prefetch, dual online-softmax states,
//                single-exp update -> merges -> fused 3-GEMV epilogue.
#define B_   8
#define OP_  400
#define MA_  200
#define ZROW (MA_ * 64)
#define NEGM -1.0e30f

typedef float v4f __attribute__((ext_vector_type(4)));

// ---------------- kernel 1: precompute (wave-per-row) ----------------
__global__ __launch_bounds__(256) void precompute_k(
    const float* __restrict__ x, const float* __restrict__ y,
    const float* __restrict__ Wop, const float* __restrict__ Wma,
    const float* __restrict__ Wedge, const float* __restrict__ att,
    float* __restrict__ ws_we, float* __restrict__ ws_eop, float* __restrict__ ws_ema)
{
    __shared__ float w_s[192];
    const int tid = threadIdx.x, wv = tid >> 6, ln = tid & 63;
    if (tid < 192) {
        const int which = tid >> 6, i = tid & 63;
        const float* W = (which == 0) ? Wop : ((which == 1) ? Wma : Wedge);
        const float* a = att + which * 64;
        float acc = 0.f;
        #pragma unroll 8
        for (int f = 0; f < 64; ++f) acc = fmaf(W[i * 64 + f], a[f], acc);
        w_s[tid] = acc;
    }
    __syncthreads();
    if (blockIdx.x == 0 && tid < 64) ws_we[tid] = w_s[128 + tid];

    const int row = blockIdx.x * 4 + wv;           // 0 .. 4799
    if (row < B_ * OP_) {
        float s = x[(size_t)row * 64 + ln] * w_s[ln];
        #pragma unroll
        for (int o = 32; o > 0; o >>= 1) s += __shfl_xor(s, o, 64);
        if (ln == 0) ws_eop[row] = s;
    } else if (row < B_ * OP_ + B_ * MA_) {
        const int r2 = row - B_ * OP_;
        float s = y[(size_t)r2 * 64 + ln] * w_s[64 + ln];
        #pragma unroll
        for (int o = 32; o > 0; o >>= 1) s += __shfl_xor(s, o, 64);
        if (ln == 0) ws_ema[r2] = s;
    }
}

// ---------------- kernel 2: fused stream + softmax + epilogue ----------------
__global__ __launch_bounds__(256) void gat_fused(
    const float* __restrict__ x, const float* __restrict__ y,
    const float* __restrict__ z, const int* __restrict__ adj,
    const float* __restrict__ Wop, const float* __restrict__ Wma,
    const float* __restrict__ Wedge,
    const float* __restrict__ ws_we, const float* __restrict__ ws_eop,
    const float* __restrict__ ws_ema, float* __restrict__ out)
{
    __shared__ int2  nle[4][112];      // packed (n, e) per wave; pad sentinels
    __shared__ float mred[4], lred[4];
    __shared__ float vws[4][64], uws[4][64];
    __shared__ float vs_s[64], us_s[64], ys_s[64];
    __shared__ float pvt[4][64];

    const int tid = threadIdx.x, wv = tid >> 6, ln = tid & 63;
    const int g = ln >> 4, q = ln & 15;            // group / feature-quad
    const int bm = blockIdx.x;
    const int b = bm / MA_, m = bm % MA_;

    const float ema = ws_ema[bm];

    // ---- per-wave active-row compaction (rows rbase..rbase+99) ----
    const int rbase = wv * 100;
    int cnt = 0;
    #pragma unroll
    for (int round = 0; round < 2; ++round) {
        const int lr = round * 64 + ln;            // 0..127
        const int n  = rbase + lr;
        bool a = false;
        if (lr < 100) a = (adj[((size_t)(b * OP_ + n)) * MA_ + m] != 0);
        const unsigned long long mask = __ballot(a);
        if (a) {
            const int pos = cnt + __popcll(mask & ((1ull << ln) - 1ull));
            nle[wv][pos] = make_int2(n, __float_as_int(ws_eop[b * OP_ + n] + ema));
        }
        cnt += __popcll(mask);
    }
    // pad through cnt_p+8 with sentinels so depth-1 prefetch is branch-free
    const int cnt_p = (cnt + 7) & ~7;              // <= 104
    if (ln < cnt_p + 8 - cnt) {                    // 8..15 lanes write
        nle[wv][cnt + ln] = make_int2(rbase, __float_as_int(NEGM));
    }
    // list is per-wave (no cross-wave reads): no barrier needed here.

    const float* zP = z + ((size_t)b * OP_ * MA_ + m) * 64;
    const float* xP = x + (size_t)b * OP_ * 64;
    const v4f wq = ((const v4f*)ws_we)[q];         // w_e quad for this lane

    // dual independent states (a-rows / b-rows) per group
    v4f v0 = {0.f,0.f,0.f,0.f}, u0 = {0.f,0.f,0.f,0.f};
    v4f v1 = {0.f,0.f,0.f,0.f}, u1 = {0.f,0.f,0.f,0.f};
    float M0 = NEGM, L0 = 0.f, M1 = NEGM, L1 = 0.f;

    // single-exp online-softmax update; 4 intra-16 shuffles shared by quad
    auto upd = [&wq](float& M, float& L, v4f& v, v4f& u,
                     const v4f z4, const v4f x4, const float eo) {
        float s_ = fmaf(z4.x, wq.x, fmaf(z4.y, wq.y,
                   fmaf(z4.z, wq.z, z4.w * wq.w)));
        s_ += __shfl_xor(s_, 1, 64); s_ += __shfl_xor(s_, 2, 64);
        s_ += __shfl_xor(s_, 4, 64); s_ += __shfl_xor(s_, 8, 64);
        float e_ = s_ + eo;
        e_ = (e_ >= 0.f) ? e_ : 0.01f * e_;
        const float m2_ = fmaxf(M, e_);
        const float w_  = __expf(fminf(M, e_) - m2_);   // one exp
        const bool  nm  = (e_ > M);
        const float c_  = nm ? w_ : 1.f;
        const float p_  = nm ? 1.f : w_;
        L = fmaf(L, c_, p_);
        v = v * c_ + z4 * p_;
        u = u * c_ + x4 * p_;
        M = m2_;
    };

    // ---- streaming pass: 8 rows/iter, depth-1 prefetch ----
    int2 pa = nle[wv][g];
    int2 pb = nle[wv][4 + g];
    v4f za = __builtin_nontemporal_load((const v4f*)(zP + (size_t)pa.x * ZROW) + q);
    v4f zb = __builtin_nontemporal_load((const v4f*)(zP + (size_t)pb.x * ZROW) + q);
    v4f xa = *((const v4f*)(xP + ((size_t)pa.x << 6)) + q);
    v4f xb = *((const v4f*)(xP + ((size_t)pb.x << 6)) + q);

    for (int i = 0; i < cnt_p; i += 8) {
        const int2 qa = nle[wv][i + 8 + g];        // prefetch next (sentinel-safe)
        const int2 qb = nle[wv][i + 12 + g];
        const v4f nza = __builtin_nontemporal_load((const v4f*)(zP + (size_t)qa.x * ZROW) + q);
        const v4f nzb = __builtin_nontemporal_load((const v4f*)(zP + (size_t)qb.x * ZROW) + q);
        const v4f nxa = *((const v4f*)(xP + ((size_t)qa.x << 6)) + q);
        const v4f nxb = *((const v4f*)(xP + ((size_t)qb.x << 6)) + q);
        upd(M0, L0, v0, u0, za, xa, __int_as_float(pa.y));
        upd(M1, L1, v1, u1, zb, xb, __int_as_float(pb.y));
        pa = qa; pb = qb; za = nza; zb = nzb; xa = nxa; xb = nxb;
    }

    // ---- merge dual states ----
    const float Mp = fmaxf(M0, M1);
    const float ca = __expf(M0 - Mp), cb = __expf(M1 - Mp);
    float L = L0 * ca + L1 * cb;
    v4f  v = v0 * ca + v1 * cb;
    v4f  u = u0 * ca + u1 * cb;
    float M = Mp;

    // ---- merge the 4 groups within the wave (xor folds over 16/32) ----
    float Mw = M;
    Mw = fmaxf(Mw, __shfl_xor(Mw, 16, 64));
    Mw = fmaxf(Mw, __shfl_xor(Mw, 32, 64));
    const float cg = __expf(M - Mw);               // per-group rescale
    float Lw = L * cg;
    Lw += __shfl_xor(Lw, 16, 64);
    Lw += __shfl_xor(Lw, 32, 64);
    v *= cg;
    u *= cg;
    v.x += __shfl_xor(v.x, 16, 64); v.y += __shfl_xor(v.y, 16, 64);
    v.z += __shfl_xor(v.z, 16, 64); v.w += __shfl_xor(v.w, 16, 64);
    v.x += __shfl_xor(v.x, 32, 64); v.y += __shfl_xor(v.y, 32, 64);
    v.z += __shfl_xor(v.z, 32, 64); v.w += __shfl_xor(v.w, 32, 64);
    u.x += __shfl_xor(u.x, 16, 64); u.y += __shfl_xor(u.y, 16, 64);
    u.z += __shfl_xor(u.z, 16, 64); u.w += __shfl_xor(u.w, 16, 64);
    u.x += __shfl_xor(u.x, 32, 64); u.y += __shfl_xor(u.y, 32, 64);
    u.z += __shfl_xor(u.z, 32, 64); u.w += __shfl_xor(u.w, 32, 64);

    if (ln < 16) {
        ((v4f*)vws[wv])[q] = v;
        ((v4f*)uws[wv])[q] = u;
    }
    if (ln == 0) { mred[wv] = Mw; lred[wv] = Lw; }
    __syncthreads();

    // ---- cross-wave online-softmax merge ----
    if (tid < 64) {
        const float Mg = fmaxf(fmaxf(mred[0], mred[1]), fmaxf(mred[2], mred[3]));
        const float c0 = __expf(mred[0] - Mg);
        const float c1 = __expf(mred[1] - Mg);
        const float c2 = __expf(mred[2] - Mg);
        const float c3 = __expf(mred[3] - Mg);
        const float Lg = c0 * lred[0] + c1 * lred[1] + c2 * lred[2] + c3 * lred[3];
        const float inv = (Lg > 0.f) ? (1.f / Lg) : 0.f;   // row_empty -> 0
        vs_s[tid] = (c0 * vws[0][tid] + c1 * vws[1][tid] +
                     c2 * vws[2][tid] + c3 * vws[3][tid]) * inv;
        us_s[tid] = (c0 * uws[0][tid] + c1 * uws[1][tid] +
                     c2 * uws[2][tid] + c3 * uws[3][tid]) * inv;
        ys_s[tid] = y[(size_t)bm * 64 + tid];
    }
    __syncthreads();

    // ---- fused epilogue: h = v@We + u@Wop + y@Wma ; waves split i ----
    {
        float acc = 0.f;
        const int i0 = wv * 16;
        #pragma unroll
        for (int k = 0; k < 16; ++k) {
            const int i = i0 + k;
            acc += vs_s[i] * Wedge[i * 64 + ln]
                 + us_s[i] * Wop[i * 64 + ln]
                 + ys_s[i] * Wma[i * 64 + ln];
        }
        pvt[wv][ln] = acc;
    }
    __syncthreads();
    if (tid < 64) {
        const float h = pvt[0][tid] + pvt[1][tid] + pvt[2][tid] + pvt[3][tid];
        out[(size_t)bm * 64 + tid] = (h > 0.f) ? h : (__expf(h) - 1.f);
    }
}

extern "C" void kernel_launch(void* const* d_in, const int* in_sizes, int n_in,
                              void* d_out, int out_size, void* d_ws, size_t ws_size,
                              hipStream_t stream) {
    const float* x     = (const float*)d_in[0];
    const float* y     = (const float*)d_in[1];
    const float* z     = (const float*)d_in[2];
    const int*   adj   = (const int*)d_in[3];
    const float* Wop   = (const float*)d_in[4];
    const float* Wma   = (const float*)d_in[5];
    const float* Wedge = (const float*)d_in[6];
    const float* att   = (const float*)d_in[7];

    float* ws     = (float*)d_ws;
    float* ws_we  = ws;                              // 64
    float* ws_eop = ws + 64;                         // B*OP = 3200
    float* ws_ema = ws + 64 + B_ * OP_;              // B*MA = 1600

    precompute_k<<<1200, 256, 0, stream>>>(
        x, y, Wop, Wma, Wedge, att, ws_we, ws_eop, ws_ema);
    gat_fused<<<B_ * MA_, 256, 0, stream>>>(
        x, y, z, adj, Wop, Wma, Wedge, ws_we, ws_eop, ws_ema, (float*)d_out);
}